// Round 5
// baseline (24640.143 us; speedup 1.0000x reference)
//
#include <hip/hip_runtime.h>

// ============================================================================
// Seq2Seq (bi-LSTM encoder + Bahdanau-attention LSTM decoder) on gfx950.
// fp32 in/out; fp16 internal (fp32 accum/state).  R5: the whole 127-step
// decoder runs in ONE persistent kernel (128 blocks, co-resident) with a
// device-scope grid barrier -- removes 254 per-step kernel launches.
// ============================================================================

typedef _Float16 f16;
typedef _Float16 half8 __attribute__((ext_vector_type(8)));
typedef float f32x4 __attribute__((ext_vector_type(4)));

#define MFMA16(a, b, c) __builtin_amdgcn_mfma_f32_16x16x32_f16((a), (b), (c), 0, 0, 0)

__device__ __forceinline__ float fsig(float x) {
    return __builtin_amdgcn_rcpf(1.f + __expf(-x));
}
__device__ __forceinline__ float ftanh(float x) {
    return 1.f - 2.f * __builtin_amdgcn_rcpf(1.f + __expf(2.f * x));
}
__device__ __forceinline__ int frag_idx(int m, int k, int KS) {
    return (((m >> 4) * KS + (k >> 5)) * 64 + (((k >> 3) & 3) * 16 + (m & 15))) * 8 + (k & 7);
}

// Device-scope grid barrier (sense via monotonically increasing generation).
__device__ __forceinline__ void gridbar(int* cnt, int* gen, int nblk) {
    __syncthreads();
    if (threadIdx.x == 0) {
        int g = __hip_atomic_load(gen, __ATOMIC_RELAXED, __HIP_MEMORY_SCOPE_AGENT);
        int v = __hip_atomic_fetch_add(cnt, 1, __ATOMIC_ACQ_REL, __HIP_MEMORY_SCOPE_AGENT);
        if (v == nblk - 1) {
            __hip_atomic_store(cnt, 0, __ATOMIC_RELAXED, __HIP_MEMORY_SCOPE_AGENT);
            __hip_atomic_fetch_add(gen, 1, __ATOMIC_ACQ_REL, __HIP_MEMORY_SCOPE_AGENT);
        } else {
            while (__hip_atomic_load(gen, __ATOMIC_ACQUIRE, __HIP_MEMORY_SCOPE_AGENT) == g)
                __builtin_amdgcn_s_sleep(2);
        }
    }
    __syncthreads();
}

// ---------------------------------------------------------------------------
// K0: one-shot: pack weights to fragment order (f32 -> f16), plain converts,
// zero out t=0 output row, zero grid-barrier counters.
// ---------------------------------------------------------------------------
__global__ __launch_bounds__(256) void k_prep(
    const float* __restrict__ attn_W, const float* __restrict__ out_W,
    const float* __restrict__ enc_emb,
    const float* __restrict__ wihf, const float* __restrict__ wihb,
    const float* __restrict__ whhf, const float* __restrict__ whhb,
    const float* __restrict__ dec_emb, const float* __restrict__ dec_wih,
    const float* __restrict__ dec_whh,
    f16* __restrict__ WhT_sw, f16* __restrict__ outWT_sw,
    f16* __restrict__ whhf_sw, f16* __restrict__ whhb_sw,
    f16* __restrict__ decwih_sw, f16* __restrict__ decwhh_sw,
    f16* __restrict__ WeT, f16* __restrict__ emb16,
    f16* __restrict__ wihf16, f16* __restrict__ wihb16,
    f16* __restrict__ decemb16, float* __restrict__ out,
    int* __restrict__ syncb)
{
    long i = (long)blockIdx.x * 256 + threadIdx.x;
    if (i >= 3784768L) return;
    long idx = i;
    if (idx < 262144) {  // WhT_sw: N=512(e) x K=512(d)
        int j = idx & 7, lane = (idx >> 3) & 63, c = lane & 15, q = lane >> 4;
        int ks = (idx >> 9) & 15, nt = idx >> 13;
        WhT_sw[idx] = (f16)attn_W[(ks * 32 + q * 8 + j) * 512 + nt * 16 + c];
        return;
    }
    idx -= 262144;
    if (idx < 65536) {   // outWT_sw: N=128(v) x K=512(d)
        int j = idx & 7, lane = (idx >> 3) & 63, c = lane & 15, q = lane >> 4;
        int ks = (idx >> 9) & 15, nt = idx >> 13;
        outWT_sw[idx] = (f16)out_W[(ks * 32 + q * 8 + j) * 128 + nt * 16 + c];
        return;
    }
    idx -= 65536;
    if (idx < 262144) {  // whhf_sw: N=1024 x K=256
        int j = idx & 7, lane = (idx >> 3) & 63, c = lane & 15, q = lane >> 4;
        int ks = (idx >> 9) & 7, nt = idx >> 12;
        whhf_sw[idx] = (f16)whhf[(nt * 16 + c) * 256 + ks * 32 + q * 8 + j];
        return;
    }
    idx -= 262144;
    if (idx < 262144) {  // whhb_sw
        int j = idx & 7, lane = (idx >> 3) & 63, c = lane & 15, q = lane >> 4;
        int ks = (idx >> 9) & 7, nt = idx >> 12;
        whhb_sw[idx] = (f16)whhb[(nt * 16 + c) * 256 + ks * 32 + q * 8 + j];
        return;
    }
    idx -= 262144;
    if (idx < 1310720) { // decwih_sw: N=2048 x K=640
        int j = idx & 7, lane = (idx >> 3) & 63, c = lane & 15, q = lane >> 4;
        int r2 = idx >> 9; int ks = r2 % 20, nt = r2 / 20;
        decwih_sw[idx] = (f16)dec_wih[(nt * 16 + c) * 640 + ks * 32 + q * 8 + j];
        return;
    }
    idx -= 1310720;
    if (idx < 1048576) { // decwhh_sw: N=2048 x K=512
        int j = idx & 7, lane = (idx >> 3) & 63, c = lane & 15, q = lane >> 4;
        int ks = (idx >> 9) & 15, nt = idx >> 13;
        decwhh_sw[idx] = (f16)dec_whh[(nt * 16 + c) * 512 + ks * 32 + q * 8 + j];
        return;
    }
    idx -= 1048576;
    if (idx < 262144) { int e = idx >> 9, d = idx & 511; WeT[idx] = (f16)attn_W[(512 + d) * 512 + e]; return; }
    idx -= 262144;
    if (idx < 16384)  { emb16[idx] = (f16)enc_emb[idx]; return; }
    idx -= 16384;
    if (idx < 131072) { wihf16[idx] = (f16)wihf[idx]; return; }
    idx -= 131072;
    if (idx < 131072) { wihb16[idx] = (f16)wihb[idx]; return; }
    idx -= 131072;
    if (idx < 16384)  { decemb16[idx] = (f16)dec_emb[idx]; return; }
    idx -= 16384;
    if (idx < 16384)  { int b = idx >> 7, v = idx & 127; out[b * 16384 + v] = 0.f; return; }
    idx -= 16384;
    if (idx < 64)     { syncb[idx] = 0; return; }
}

// ---------------------------------------------------------------------------
// K_vocab: xg_vocab[v][n] = emb[v] @ [Wih_f|Wih_b]^T + [b_f|b_b] (once).
// ---------------------------------------------------------------------------
__global__ __launch_bounds__(256) void k_vocab(
    const f16* __restrict__ emb, const f16* __restrict__ wihf,
    const f16* __restrict__ wihb, const float* __restrict__ bf_,
    const float* __restrict__ bb_, f16* __restrict__ xg_vocab)
{
    int bn = blockIdx.x;
    int tid = threadIdx.x, wave = tid >> 6, lane = tid & 63;
    int col = lane & 15, quad = lane >> 4;
    int wr = wave >> 1, wc = wave & 1;

    f32x4 acc[4][4] = {};
    for (int ks = 0; ks < 4; ++ks) {
        int k0 = ks * 32 + quad * 8;
        half8 a[4], bfr[4];
        for (int i = 0; i < 4; ++i)
            a[i] = *(const half8*)(emb + (wr * 64 + i * 16 + col) * 128 + k0);
        for (int j = 0; j < 4; ++j) {
            int n = bn * 128 + wc * 64 + j * 16 + col;
            const f16* wp = (n < 1024) ? (wihf + n * 128) : (wihb + (n - 1024) * 128);
            bfr[j] = *(const half8*)(wp + k0);
        }
        for (int i = 0; i < 4; ++i)
            for (int j = 0; j < 4; ++j)
                acc[i][j] = MFMA16(a[i], bfr[j], acc[i][j]);
    }
    for (int j = 0; j < 4; ++j) {
        int n = bn * 128 + wc * 64 + j * 16 + col;
        float bias = (n < 1024) ? bf_[n] : bb_[n - 1024];
        for (int i = 0; i < 4; ++i) {
            int vbase = wr * 64 + i * 16 + quad * 4;
            for (int r = 0; r < 4; ++r)
                xg_vocab[(vbase + r) * 2048 + n] = (f16)(acc[i][j][r] + bias);
        }
    }
}

// ---------------------------------------------------------------------------
// K_enc: encoder scan, 16 persistent blocks (2 dir x 8 batch-groups of 16),
// 512 threads.  (unchanged from R4 -- known correct)
// ---------------------------------------------------------------------------
__global__ __launch_bounds__(512) void k_enc(
    const int* __restrict__ src, const f16* __restrict__ xg_vocab,
    const f16* __restrict__ whhf_sw, const f16* __restrict__ whhb_sw,
    f16* __restrict__ enc_out, f16* __restrict__ hdec0, float* __restrict__ c_ws)
{
    int blk = blockIdx.x;
    int dir = blk >> 3, bbase = (blk & 7) * 16;
    int tid = threadIdx.x, wave = tid >> 6, lane = tid & 63;
    int col = lane & 15, quad = lane >> 4;
    const f16* whh = dir ? whhb_sw : whhf_sw;

    __shared__ f16 hb[16][264];
    __shared__ f16 xvb[16][1032];
    __shared__ int stok[16];
    for (int z = tid; z < 16 * 264; z += 512) ((f16*)hb)[z] = (f16)0.f;
    float cc[2][4] = {};
    __syncthreads();

    for (int t = 0; t < 512; ++t) {
        int ts = dir ? (511 - t) : t;
        if (tid < 16) stok[tid] = src[(bbase + tid) * 512 + ts];
        half8 a[8];
        #pragma unroll
        for (int kk = 0; kk < 8; ++kk)
            a[kk] = *(const half8*)(&hb[col][kk * 32 + quad * 8]);
        __syncthreads();

        #pragma unroll
        for (int it = 0; it < 4; ++it) {
            int cnk = it * 512 + tid;
            int row = cnk >> 7, off = (cnk & 127) * 8;
            *(half8*)(&xvb[row][off]) =
                *(const half8*)(xg_vocab + stok[row] * 2048 + dir * 1024 + off);
        }

        f32x4 acc[4][2] = {};
        #pragma unroll
        for (int kk = 0; kk < 8; ++kk) {
            half8 bv[8];
            #pragma unroll
            for (int g = 0; g < 4; ++g)
                #pragma unroll
                for (int nt = 0; nt < 2; ++nt) {
                    int tile = g * 16 + wave * 2 + nt;
                    bv[g * 2 + nt] = *(const half8*)(whh + ((tile * 8 + kk) * 64 + lane) * 8);
                }
            #pragma unroll
            for (int g = 0; g < 4; ++g)
                #pragma unroll
                for (int nt = 0; nt < 2; ++nt)
                    acc[g][nt] = MFMA16(a[kk], bv[g * 2 + nt], acc[g][nt]);
        }
        __syncthreads();

        #pragma unroll
        for (int nt = 0; nt < 2; ++nt) {
            int hcol = wave * 32 + nt * 16 + col;
            #pragma unroll
            for (int r = 0; r < 4; ++r) {
                int b = quad * 4 + r;
                float gi = (float)xvb[b][0 * 256 + hcol] + acc[0][nt][r];
                float gf = (float)xvb[b][1 * 256 + hcol] + acc[1][nt][r];
                float gg = (float)xvb[b][2 * 256 + hcol] + acc[2][nt][r];
                float go = (float)xvb[b][3 * 256 + hcol] + acc[3][nt][r];
                float ig = fsig(gi), fg = fsig(gf), g2 = ftanh(gg), og = fsig(go);
                float cv = fg * cc[nt][r] + ig * g2;
                cc[nt][r] = cv;
                float h = og * ftanh(cv);
                f16 h16 = (f16)h;
                hb[b][hcol] = h16;
                enc_out[((size_t)(bbase + b) * 512 + ts) * 512 + dir * 256 + hcol] = h16;
            }
        }
        __syncthreads();
    }
    #pragma unroll
    for (int nt = 0; nt < 2; ++nt) {
        int hcol = wave * 32 + nt * 16 + col;
        #pragma unroll
        for (int r = 0; r < 4; ++r) {
            int b = quad * 4 + r;
            int m = bbase + b, k = dir * 256 + hcol;
            hdec0[frag_idx(m, k, 16)] = hb[b][hcol];
            c_ws[m * 512 + k] = cc[nt][r];
        }
    }
}

// ---------------------------------------------------------------------------
// K_proj: enc_proj = enc_out @ We (once).
// ---------------------------------------------------------------------------
__global__ __launch_bounds__(256) void k_proj(
    const f16* __restrict__ enc_out, const f16* __restrict__ WeT,
    f16* __restrict__ proj)
{
    int blk = blockIdx.x;
    int bm = blk & 511, bn = blk >> 9;
    int tid = threadIdx.x, wave = tid >> 6, lane = tid & 63;
    int col = lane & 15, quad = lane >> 4;
    int wr = wave >> 1, wc = wave & 1;

    f32x4 acc[4][4] = {};
    for (int ks = 0; ks < 16; ++ks) {
        int k0 = ks * 32 + quad * 8;
        half8 a[4], bfr[4];
        for (int i = 0; i < 4; ++i) {
            int m = bm * 128 + wr * 64 + i * 16 + col;
            a[i] = *(const half8*)(enc_out + (size_t)m * 512 + k0);
        }
        for (int j = 0; j < 4; ++j) {
            int n = bn * 128 + wc * 64 + j * 16 + col;
            bfr[j] = *(const half8*)(WeT + n * 512 + k0);
        }
        for (int i = 0; i < 4; ++i)
            for (int j = 0; j < 4; ++j)
                acc[i][j] = MFMA16(a[i], bfr[j], acc[i][j]);
    }
    for (int j = 0; j < 4; ++j) {
        int n = bn * 128 + wc * 64 + j * 16 + col;
        for (int i = 0; i < 4; ++i) {
            int mbase = bm * 128 + wr * 64 + i * 16 + quad * 4;
            for (int r = 0; r < 4; ++r)
                proj[(size_t)(mbase + r) * 512 + n] = (f16)acc[i][j][r];
        }
    }
}

// ---------------------------------------------------------------------------
// K_qinit: initial q-partials (once).
// ---------------------------------------------------------------------------
__global__ __launch_bounds__(256) void k_qinit(
    const f16* __restrict__ h0_sw, const f16* __restrict__ WhT_sw,
    float* __restrict__ qpart)
{
    int j = blockIdx.x;
    int tid = threadIdx.x, wave = tid >> 6, lane = tid & 63;
    int col = lane & 15, quad = lane >> 4;
    half8 a[2];
    #pragma unroll
    for (int i = 0; i < 2; ++i)
        a[i] = *(const half8*)(h0_sw + (((wave * 2 + i) * 16 + j) * 64 + lane) * 8);
    for (int nt = 0; nt < 32; ++nt) {
        half8 bfr = *(const half8*)(WhT_sw + ((nt * 16 + j) * 64 + lane) * 8);
        f32x4 q0 = {}, q1 = {};
        q0 = MFMA16(a[0], bfr, q0);
        q1 = MFMA16(a[1], bfr, q1);
        #pragma unroll
        for (int r = 0; r < 4; ++r) {
            qpart[(j * 128 + wave * 32 + quad * 4 + r) * 512 + nt * 16 + col] = q0[r];
            qpart[(j * 128 + wave * 32 + 16 + quad * 4 + r) * 512 + nt * 16 + col] = q1[r];
        }
    }
}

// ---------------------------------------------------------------------------
// K_dec: the whole 127-step decoder, persistent.  128 blocks x 512 threads.
// Per step: ATT (all blocks; block = batch row) | gridbar | GATES (blocks
// 0-15, waves 0-3, R4 structure) | gridbar.
// ---------------------------------------------------------------------------
__global__ __launch_bounds__(512) void k_dec(
    const f16* __restrict__ proj, const f16* __restrict__ enc_out,
    float* __restrict__ qpart, const float* __restrict__ attn_b,
    const float* __restrict__ attn_v, const int* __restrict__ trg,
    const f16* __restrict__ decemb, f16* __restrict__ x_sw,
    const f16* __restrict__ wih_sw, const f16* __restrict__ whh_sw,
    const float* __restrict__ dec_b, float* __restrict__ c_ws,
    f16* __restrict__ hd0, f16* __restrict__ hd1, f16* __restrict__ hhist_sw,
    const f16* __restrict__ WhT_sw, int* __restrict__ syncb)
{
    int blk = blockIdx.x;
    int tid = threadIdx.x, wave = tid >> 6, lane = tid & 63;
    int col = lane & 15, quad = lane >> 4;
    int nblk = gridDim.x;
    int* cnt = syncb;
    int* gen = syncb + 16;

    __shared__ float q[512];
    __shared__ float sc[512];
    __shared__ float ctxred[8][512];
    __shared__ float wred[8], wred2[8];
    __shared__ f16 hsl[128][40];

    float vreg[8];
    #pragma unroll
    for (int u = 0; u < 8; ++u) vreg[u] = attn_v[lane * 8 + u];
    float bias[8];
    if (blk < 16) {
        #pragma unroll
        for (int jt = 0; jt < 8; ++jt) {
            int g = jt >> 1, u2 = jt & 1;
            bias[jt] = dec_b[g * 512 + blk * 32 + u2 * 16 + col];
        }
    }

    for (int t = 0; t < 127; ++t) {
        // ================= ATT phase: b = blk =================
        int b = blk;
        {
            float s0 = attn_b[tid];
            #pragma unroll
            for (int jj = 0; jj < 16; ++jj) s0 += qpart[(jj * 128 + b) * 512 + tid];
            q[tid] = s0;
        }
        __syncthreads();
        float qreg[8];
        #pragma unroll
        for (int u = 0; u < 8; ++u) qreg[u] = q[lane * 8 + u];

        // scores: wave w owns s = z8*8 + w, 8-deep batched loads
        for (int ib = 0; ib < 8; ++ib) {
            half8 p[8];
            #pragma unroll
            for (int z = 0; z < 8; ++z) {
                int s = (ib * 8 + z) * 8 + wave;
                p[z] = *(const half8*)(proj + ((size_t)b * 512 + s) * 512 + lane * 8);
            }
            #pragma unroll
            for (int z = 0; z < 8; ++z) {
                int s = (ib * 8 + z) * 8 + wave;
                float part = 0.f;
                #pragma unroll
                for (int u = 0; u < 8; ++u)
                    part += vreg[u] * ftanh(qreg[u] + (float)p[z][u]);
                #pragma unroll
                for (int o = 32; o; o >>= 1) part += __shfl_xor(part, o);
                if (lane == 0) sc[s] = part;
            }
        }
        __syncthreads();

        // softmax over 512
        float sv = sc[tid];
        float mv = sv;
        #pragma unroll
        for (int o = 32; o; o >>= 1) mv = fmaxf(mv, __shfl_xor(mv, o));
        if (lane == 0) wred[wave] = mv;
        __syncthreads();
        float M = wred[0];
        #pragma unroll
        for (int w = 1; w < 8; ++w) M = fmaxf(M, wred[w]);
        float e0 = __expf(sv - M);
        float sm = e0;
        #pragma unroll
        for (int o = 32; o; o >>= 1) sm += __shfl_xor(sm, o);
        if (lane == 0) wred2[wave] = sm;
        __syncthreads();
        float den = wred2[0];
        #pragma unroll
        for (int w = 1; w < 8; ++w) den += wred2[w];
        sc[tid] = e0 * (1.f / den);
        __syncthreads();

        // ctx: wave owns 64 s-rows; lane owns d = lane*8..+8; 8-deep batching
        float a8[8] = {};
        int sbase = wave * 64;
        for (int i8 = 0; i8 < 8; ++i8) {
            half8 ev[8];
            #pragma unroll
            for (int z = 0; z < 8; ++z) {
                int s = sbase + i8 * 8 + z;
                ev[z] = *(const half8*)(enc_out + ((size_t)b * 512 + s) * 512 + lane * 8);
            }
            #pragma unroll
            for (int z = 0; z < 8; ++z) {
                float wgt = sc[sbase + i8 * 8 + z];
                #pragma unroll
                for (int u = 0; u < 8; ++u) a8[u] += wgt * (float)ev[z][u];
            }
        }
        #pragma unroll
        for (int u = 0; u < 8; ++u) ctxred[wave][lane * 8 + u] = a8[u];
        __syncthreads();
        float ctx = 0.f;
        #pragma unroll
        for (int w = 0; w < 8; ++w) ctx += ctxred[w][tid];

        int tok = trg[b * 128 + t];
        if (tid < 128) x_sw[frag_idx(b, tid, 20)] = decemb[tok * 128 + tid];
        x_sw[frag_idx(b, 128 + tid, 20)] = (f16)ctx;

        gridbar(cnt, gen, nblk);

        // ================= GATES phase: blocks 0-15, waves 0-3 =================
        if (blk < 16 && wave < 4) {
            const f16* hprev = (t & 1) ? hd1 : hd0;
            f16* hnext = (t & 1) ? hd0 : hd1;
            int j = blk;

            f32x4 acc[2][8] = {};
            for (int ks = 0; ks < 36; ++ks) {
                half8 a[2];
                #pragma unroll
                for (int i = 0; i < 2; ++i) {
                    int mtile = wave * 2 + i;
                    a[i] = (ks < 20)
                        ? *(const half8*)(x_sw + ((mtile * 20 + ks) * 64 + lane) * 8)
                        : *(const half8*)(hprev + ((mtile * 16 + (ks - 20)) * 64 + lane) * 8);
                }
                half8 bv[8];
                #pragma unroll
                for (int jt = 0; jt < 8; ++jt) {
                    int g = jt >> 1, u2 = jt & 1;
                    int ntile = g * 32 + j * 2 + u2;
                    bv[jt] = (ks < 20)
                        ? *(const half8*)(wih_sw + ((ntile * 20 + ks) * 64 + lane) * 8)
                        : *(const half8*)(whh_sw + ((ntile * 16 + (ks - 20)) * 64 + lane) * 8);
                }
                #pragma unroll
                for (int jt = 0; jt < 8; ++jt) {
                    acc[0][jt] = MFMA16(a[0], bv[jt], acc[0][jt]);
                    acc[1][jt] = MFMA16(a[1], bv[jt], acc[1][jt]);
                }
            }
            #pragma unroll
            for (int i = 0; i < 2; ++i) {
                #pragma unroll
                for (int r = 0; r < 4; ++r) {
                    int bb = wave * 32 + i * 16 + quad * 4 + r;
                    #pragma unroll
                    for (int u2 = 0; u2 < 2; ++u2) {
                        int hl = u2 * 16 + col, hcol = j * 32 + hl;
                        float gi = acc[i][0 + u2][r] + bias[0 + u2];
                        float gf = acc[i][2 + u2][r] + bias[2 + u2];
                        float gg = acc[i][4 + u2][r] + bias[4 + u2];
                        float go = acc[i][6 + u2][r] + bias[6 + u2];
                        float ig = fsig(gi), fg = fsig(gf), g2 = ftanh(gg), og = fsig(go);
                        float cv = fg * c_ws[bb * 512 + hcol] + ig * g2;
                        c_ws[bb * 512 + hcol] = cv;
                        float h = og * ftanh(cv);
                        f16 h16 = (f16)h;
                        int fidx = frag_idx(bb, hcol, 16);
                        hnext[fidx] = h16;
                        hhist_sw[t * 65536 + fidx] = h16;
                        hsl[bb][hl] = h16;
                    }
                }
            }
            // fused q-partials for next step
            half8 aq[2];
            #pragma unroll
            for (int i = 0; i < 2; ++i)
                aq[i] = *(const half8*)(&hsl[wave * 32 + i * 16 + col][quad * 8]);
            for (int nt = 0; nt < 32; ++nt) {
                half8 bq = *(const half8*)(WhT_sw + ((nt * 16 + j) * 64 + lane) * 8);
                f32x4 q0 = {}, q1 = {};
                q0 = MFMA16(aq[0], bq, q0);
                q1 = MFMA16(aq[1], bq, q1);
                #pragma unroll
                for (int r = 0; r < 4; ++r) {
                    qpart[(j * 128 + wave * 32 + quad * 4 + r) * 512 + nt * 16 + col] = q0[r];
                    qpart[(j * 128 + wave * 32 + 16 + quad * 4 + r) * 512 + nt * 16 + col] = q1[r];
                }
            }
        }
        gridbar(cnt, gen, nblk);
    }
}

// ---------------------------------------------------------------------------
// K_logits: batched over all 127 steps (once).
// ---------------------------------------------------------------------------
__global__ __launch_bounds__(256) void k_logits(
    const f16* __restrict__ hhist_sw, const f16* __restrict__ outWT_sw,
    const float* __restrict__ out_b, float* __restrict__ out)
{
    int bt = blockIdx.x;
    int tid = threadIdx.x, wave = tid >> 6, lane = tid & 63;
    int col = lane & 15, quad = lane >> 4;
    f32x4 acc[2][8] = {};
    for (int ks = 0; ks < 16; ++ks) {
        half8 a[2];
        #pragma unroll
        for (int i = 0; i < 2; ++i)
            a[i] = *(const half8*)(hhist_sw + bt * 65536 + (((wave * 2 + i) * 16 + ks) * 64 + lane) * 8);
        half8 bv[8];
        #pragma unroll
        for (int jt = 0; jt < 8; ++jt)
            bv[jt] = *(const half8*)(outWT_sw + ((jt * 16 + ks) * 64 + lane) * 8);
        #pragma unroll
        for (int jt = 0; jt < 8; ++jt) {
            acc[0][jt] = MFMA16(a[0], bv[jt], acc[0][jt]);
            acc[1][jt] = MFMA16(a[1], bv[jt], acc[1][jt]);
        }
    }
    #pragma unroll
    for (int jt = 0; jt < 8; ++jt) {
        float bias = out_b[jt * 16 + col];
        #pragma unroll
        for (int i = 0; i < 2; ++i)
            #pragma unroll
            for (int r = 0; r < 4; ++r) {
                int br = wave * 32 + i * 16 + quad * 4 + r;
                out[br * 16384 + (bt + 1) * 128 + jt * 16 + col] = acc[i][jt][r] + bias;
            }
    }
}

// ---------------------------------------------------------------------------
extern "C" void kernel_launch(void* const* d_in, const int* in_sizes, int n_in,
                              void* d_out, int out_size, void* d_ws, size_t ws_size,
                              hipStream_t stream)
{
    (void)in_sizes; (void)n_in; (void)out_size;
    if (ws_size < 164000000) return;  // clean bail if workspace too small

    const int*   src     = (const int*)d_in[0];
    const int*   trg     = (const int*)d_in[1];
    const float* enc_emb = (const float*)d_in[2];
    const float* wihf    = (const float*)d_in[3];
    const float* whhf    = (const float*)d_in[4];
    const float* bf_     = (const float*)d_in[5];
    const float* wihb    = (const float*)d_in[6];
    const float* whhb    = (const float*)d_in[7];
    const float* bb_     = (const float*)d_in[8];
    const float* dec_emb = (const float*)d_in[9];
    const float* dec_wih = (const float*)d_in[10];
    const float* dec_whh = (const float*)d_in[11];
    const float* dec_b   = (const float*)d_in[12];
    const float* attn_W  = (const float*)d_in[13];
    const float* attn_b  = (const float*)d_in[14];
    const float* attn_v  = (const float*)d_in[15];
    const float* out_W   = (const float*)d_in[16];
    const float* out_b   = (const float*)d_in[17];
    float* out = (float*)d_out;

    char* p = (char*)d_ws;
    auto carve = [&](size_t n) { char* r = p; p += ((n + 255) & ~(size_t)255); return r; };
    f16*   enc_out   = (f16*)  carve(67108864);
    f16*   proj      = (f16*)  carve(67108864);
    f16*   WhT_sw    = (f16*)  carve(524288);
    f16*   WeT       = (f16*)  carve(524288);
    f16*   outWT_sw  = (f16*)  carve(131072);
    f16*   emb16     = (f16*)  carve(32768);
    f16*   wihf16    = (f16*)  carve(262144);
    f16*   wihb16    = (f16*)  carve(262144);
    f16*   whhf_sw   = (f16*)  carve(524288);
    f16*   whhb_sw   = (f16*)  carve(524288);
    f16*   decemb16  = (f16*)  carve(32768);
    f16*   decwih_sw = (f16*)  carve(2621440);
    f16*   decwhh_sw = (f16*)  carve(2097152);
    float* qpart     = (float*)carve(4194304);
    f16*   hdec0     = (f16*)  carve(131072);
    f16*   hdec1     = (f16*)  carve(131072);
    float* c_ws      = (float*)carve(262144);
    f16*   x_sw      = (f16*)  carve(163840);
    f16*   hhist_sw  = (f16*)  carve(16646144);
    f16*   xg_vocab  = (f16*)  carve(524288);
    int*   syncb     = (int*)  carve(256);

    k_prep<<<14785, 256, 0, stream>>>(attn_W, out_W, enc_emb, wihf, wihb, whhf, whhb,
                                      dec_emb, dec_wih, dec_whh,
                                      WhT_sw, outWT_sw, whhf_sw, whhb_sw,
                                      decwih_sw, decwhh_sw, WeT, emb16,
                                      wihf16, wihb16, decemb16, out, syncb);
    k_vocab<<<16, 256, 0, stream>>>(emb16, wihf16, wihb16, bf_, bb_, xg_vocab);
    k_enc<<<16, 512, 0, stream>>>(src, xg_vocab, whhf_sw, whhb_sw, enc_out, hdec0, c_ws);
    k_proj<<<2048, 256, 0, stream>>>(enc_out, WeT, proj);
    k_qinit<<<16, 256, 0, stream>>>(hdec0, WhT_sw, qpart);
    k_dec<<<128, 512, 0, stream>>>(proj, enc_out, qpart, attn_b, attn_v, trg,
                                   decemb16, x_sw, decwih_sw, decwhh_sw, dec_b,
                                   c_ws, hdec0, hdec1, hhist_sw, WhT_sw, syncb);
    k_logits<<<127, 256, 0, stream>>>(hhist_sw, outWT_sw, out_b, out);
}